// Round 18
// baseline (229.574 us; speedup 1.0000x reference)
//
#include <hip/hip_runtime.h>
#include <hip/hip_bf16.h>
#include <stdint.h>

#define TOK   16384
#define DIM   256
#define HIDN  1024
#define OUTD  256
#define NEXP  8
#define NSH   3
#define NSLOT 11
#define TM    64
#define NCH   16      // hidden chunks of 64 cols
#define HSTR  72      // H row stride in shorts (144B = 9x16B: b128-aligned, 2-way banks)

typedef short bf16x8  __attribute__((ext_vector_type(8)));
typedef float f32x4   __attribute__((ext_vector_type(4)));
typedef short short4v __attribute__((ext_vector_type(4)));

// ---- workspace layout (bytes) ----
constexpr size_t XB_OFF   = 0;                                        // T*D bf16
constexpr size_t W1P_OFF  = XB_OFF  + (size_t)TOK*DIM*2;
constexpr size_t W2P_OFF  = W1P_OFF + (size_t)NSLOT*DIM*HIDN*2;
constexpr size_t WTS_OFF  = W2P_OFF + (size_t)NSLOT*HIDN*OUTD*2;
constexpr size_t IDS_OFF  = WTS_OFF + (size_t)TOK*2*4;
constexpr size_t CNT_OFF  = IDS_OFF + (size_t)TOK*2*4;
constexpr size_t LTOK_OFF = CNT_OFF + 256;
constexpr size_t LW_OFF   = LTOK_OFF + (size_t)NEXP*TOK*4;
constexpr size_t WS_NEED  = LW_OFF + (size_t)NEXP*TOK*4;

__device__ __forceinline__ unsigned short f2bf(float f) {
    __hip_bfloat16 h = __float2bfloat16(f);
    return *reinterpret_cast<unsigned short*>(&h);
}

__device__ __forceinline__ f32x4 mfma16(bf16x8 a, bf16x8 b, f32x4 c) {
    return __builtin_amdgcn_mfma_f32_16x16x32_bf16(a, b, c, 0, 0, 0);
}

// async global->LDS: 16B/lane; global src per-lane, LDS dst uniform base.
__device__ __forceinline__ void gload_lds16(const void* g, void* l) {
    __builtin_amdgcn_global_load_lds(
        (const __attribute__((address_space(1))) unsigned int*)g,
        (__attribute__((address_space(3))) unsigned int*)l, 16, 0, 0);
}

__device__ __forceinline__ void fence_sched() { __builtin_amdgcn_sched_barrier(0); }

// ---- fused: fp32->bf16 convert of X + fp32-exact gating (one X pass) ----
__global__ __launch_bounds__(256) void k_prep(
    const float* __restrict__ x, const float* __restrict__ gw,
    const float* __restrict__ gb, short* __restrict__ xb,
    float* __restrict__ wts, int* __restrict__ ids) {
    int wid = threadIdx.x >> 6, lane = threadIdx.x & 63;
    int t = blockIdx.x * 4 + wid;
    const float* xr = x + (size_t)t * DIM;
    {
        float4 v = reinterpret_cast<const float4*>(xr)[lane];
        short4v o;
        o[0] = (short)f2bf(v.x); o[1] = (short)f2bf(v.y);
        o[2] = (short)f2bf(v.z); o[3] = (short)f2bf(v.w);
        reinterpret_cast<short4v*>(xb + (size_t)t * DIM)[lane] = o;
    }
    float acc[NEXP] = {0.f,0.f,0.f,0.f,0.f,0.f,0.f,0.f};
    #pragma unroll
    for (int i = 0; i < DIM/64; ++i) {
        int d = i*64 + lane;
        float xv = xr[d];
        const float* g = gw + (size_t)d * NEXP;
        #pragma unroll
        for (int e = 0; e < NEXP; ++e) acc[e] = fmaf(xv, g[e], acc[e]);
    }
    #pragma unroll
    for (int off = 32; off; off >>= 1) {
        #pragma unroll
        for (int e = 0; e < NEXP; ++e) acc[e] += __shfl_xor(acc[e], off, 64);
    }
    if (lane == 0) {
        float l[NEXP];
        #pragma unroll
        for (int e = 0; e < NEXP; ++e) l[e] = acc[e] + gb[e];
        int e0 = 0; float v0 = l[0];
        #pragma unroll
        for (int e = 1; e < NEXP; ++e) if (l[e] > v0) { v0 = l[e]; e0 = e; }
        int e1 = -1; float v1 = -1e30f;
        #pragma unroll
        for (int e = 0; e < NEXP; ++e) if (e != e0 && l[e] > v1) { v1 = l[e]; e1 = e; }
        float r = expf(v1 - v0);
        float w0 = 0.5f / (1.f + r);
        float w1 = 0.5f * r / (1.f + r);
        ids[2*t]   = e0;  ids[2*t+1] = e1;
        wts[2*t]   = w0;  wts[2*t+1] = w1;
    }
}

// ---- fp32 weights -> bf16 packed B-frag order, via LDS transpose ----
__global__ __launch_bounds__(256) void k_convert_w(
    const float* __restrict__ sw1, const float* __restrict__ iw1,
    const float* __restrict__ sw2, const float* __restrict__ iw2,
    short* __restrict__ w1p, short* __restrict__ w2p) {
    __shared__ float tile[32][68];
    int bid = blockIdx.x, tid = threadIdx.x;
    const int W1B = NSLOT * 8 * 16;            // 1408
    bool isW1 = bid < W1B;
    int b = isW1 ? bid : bid - W1B;
    int NTG = isW1 ? 16 : 4;
    int KT  = isW1 ? 8 : 32;
    int NT  = isW1 ? 64 : 16;
    int Nd  = isW1 ? HIDN : OUTD;
    int ntg = b % NTG; b /= NTG;
    int kt  = b % KT;
    int slot = b / KT;
    const float* src;
    if (isW1) src = (slot < NSH) ? sw1 + (size_t)slot*DIM*HIDN  : iw1 + (size_t)(slot-NSH)*DIM*HIDN;
    else      src = (slot < NSH) ? sw2 + (size_t)slot*HIDN*OUTD : iw2 + (size_t)(slot-NSH)*HIDN*OUTD;
    {
        int tr = tid >> 3, tc = (tid & 7) * 8;
        const float* s = src + (size_t)(kt*32 + tr)*Nd + ntg*64 + tc;
        float4 v0 = *reinterpret_cast<const float4*>(s);
        float4 v1 = *reinterpret_cast<const float4*>(s + 4);
        *reinterpret_cast<float4*>(&tile[tr][tc])     = v0;
        *reinterpret_cast<float4*>(&tile[tr][tc + 4]) = v1;
    }
    __syncthreads();
    {
        int ntl = tid >> 6, lane = tid & 63;
        int n  = ntl*16 + (lane & 15);
        int k8 = (lane >> 4) * 8;
        bf16x8 o;
        #pragma unroll
        for (int j = 0; j < 8; ++j) o[j] = (short)f2bf(tile[k8 + j][n]);
        size_t gidx = (((size_t)slot*KT + kt)*NT + ntg*4 + ntl)*64 + lane;
        short* dst = isW1 ? w1p : w2p;
        reinterpret_cast<bf16x8*>(dst)[gidx] = o;
    }
}

// ---- route: LDS histogram -> 8 global atomics per block ----
__global__ __launch_bounds__(256) void k_route(
    const int* __restrict__ ids, const float* __restrict__ wts,
    int* __restrict__ cnt, int* __restrict__ ltok, float* __restrict__ lw) {
    __shared__ int lcnt[NEXP];
    __shared__ int gbase[NEXP];
    int tid = threadIdx.x;
    if (tid < NEXP) lcnt[tid] = 0;
    __syncthreads();
    int t = blockIdx.x * 256 + tid;
    int e0 = ids[2*t], e1 = ids[2*t+1];
    int p0 = atomicAdd(&lcnt[e0], 1);
    int p1 = atomicAdd(&lcnt[e1], 1);
    __syncthreads();
    if (tid < NEXP) gbase[tid] = atomicAdd(&cnt[tid], lcnt[tid]);
    __syncthreads();
    size_t o0 = (size_t)e0*TOK + gbase[e0] + p0;
    size_t o1 = (size_t)e1*TOK + gbase[e1] + p1;
    ltok[o0] = t;  lw[o0] = wts[2*t];
    ltok[o1] = t;  lw[o1] = wts[2*t+1];
}

// ---- mega-kernel v14: 4-wave blocks, CW=64, 2m x 2n both phases ----
// r17 post-mortem: LDS-issue volume is the bound (0.875 b128/MFMA). Bigger
// per-wave tiles cut reads/MFMA: phase1 32x32 (0.5 B-reads/MFMA, areg[2][8]),
// phase2 32x128 (acc2[2][8], W2-dup 2x, H-dup 2x). 4-wave blocks keep
// 2 blocks/CU despite ~180 regs (m97's small-block trick). LDS 78KB.
__global__ __launch_bounds__(256) void k_moe(
    const short* __restrict__ xb, const short* __restrict__ w1p, const short* __restrict__ w2p,
    const float* __restrict__ sb1, const float* __restrict__ sb2,
    const float* __restrict__ ib1, const float* __restrict__ ib2,
    const float* __restrict__ obj, const int* __restrict__ cnt,
    const int* __restrict__ ltok, const float* __restrict__ lw,
    float* __restrict__ out)
{
    __shared__ __align__(16) char Wb1[32768];      // [kt 0..7][ntl 0..3] x 1KB
    __shared__ __align__(16) char Wb2[32768];      // [k2 0..1][nt 0..15] x 1KB
    __shared__ __align__(16) short Hs[TM * HSTR];  // 64 x 72 shorts (144B stride)
    __shared__ float bias_lds[HIDN];               // b1 (4KB)
    __shared__ int   tokl[TM];
    __shared__ float twl[TM];

    const int slot = blockIdx.y;
    const int m0   = blockIdx.x * TM;
    const bool sh  = slot < NSH;
    const int e    = slot - NSH;
    int count = TOK;
    if (!sh) { count = cnt[e]; if (m0 >= count) return; }

    const int tid  = threadIdx.x;
    const int w    = tid >> 6, lane = tid & 63;
    const int wm   = w >> 1,   wn   = w & 1;       // 2m x 2n (both phases)
    const int lrow = lane & 15, g   = lane >> 4;

    if (tid < TM) {
        if (sh) {
            tokl[tid] = m0 + tid;
            twl[tid]  = 0.5f * obj[(size_t)(m0 + tid)*NSH + slot];
        } else {
            int p = m0 + tid;
            bool ok = p < count;
            tokl[tid] = ok ? ltok[(size_t)e*TOK + p] : 0;
            twl[tid]  = ok ? lw[(size_t)e*TOK + p] : 0.f;   // already 0.5-scaled
        }
    }
    __syncthreads();                               // tokl visible

    const char* w1base = (const char*)w1p;
    const char* w2base = (const char*)w2p;
    const float* b1v = sh ? (sb1 + slot*HIDN) : (ib1 + (size_t)e*HIDN);

    // ---- A-frags (2 x 16 rows) -> registers, once (chunk-invariant) ----
    const int tokA0 = tokl[wm*32 + 0*16 + lrow];
    const int tokA1 = tokl[wm*32 + 1*16 + lrow];
    bf16x8 areg[2][8];
    #pragma unroll
    for (int kt = 0; kt < 8; ++kt) {
        areg[0][kt] = *reinterpret_cast<const bf16x8*>(
            xb + (size_t)tokA0*DIM + kt*32 + g*8);
        areg[1][kt] = *reinterpret_cast<const bf16x8*>(
            xb + (size_t)tokA1*DIM + kt*32 + g*8);
    }

    // bias 4KB: all 4 waves
    gload_lds16((const char*)b1v + w*1024 + lane*16, (char*)bias_lds + w*1024);

    // stage W1 chunk c (32KB): wave w stages idx = w*8+i; kt = idx>>2, ntl = idx&3
    auto stage_w1 = [&](int c) {
        #pragma unroll
        for (int i = 0; i < 8; ++i) {
            int idx = w*8 + i;
            gload_lds16(
                w1base + ((((size_t)slot*8 + (idx >> 2))*64 + c*4 + (idx & 3)) << 10) + lane*16,
                Wb1 + (idx << 10));
        }
    };
    // stage W2 chunk c (32KB contiguous): wave w stages idx = w*8+i
    auto stage_w2 = [&](int c) {
        const char* s2 = w2base + ((((size_t)slot*32 + c*2)*16) << 10);
        #pragma unroll
        for (int i = 0; i < 8; ++i) {
            int idx = w*8 + i;
            gload_lds16(s2 + (idx << 10) + lane*16, Wb2 + (idx << 10));
        }
    };

    stage_w1(0);
    stage_w2(0);
    // hard drain: areg/bias/stage(0) complete; loop VMEM = staging only
    asm volatile("s_waitcnt vmcnt(0) lgkmcnt(0)" ::: "memory");
    __syncthreads();

    f32x4 acc2[2][8] = {};                         // phase-2 wave tile 32 x 128
    for (int c = 0; c < NCH; ++c) {
        if (c > 0) {
            stage_w2(c);                           // Wb2 free since last barrier
            fence_sched();
            asm volatile("s_waitcnt vmcnt(8)" ::: "memory");   // W1(c) landed
            fence_sched();
            __builtin_amdgcn_s_barrier();
            fence_sched();
        }

        // ---- phase 1 (2m x 2n): acc1 = X(regs) @ W1c, wave 32r x 32c ----
        f32x4 acc1[2][2] = {};
        #pragma unroll
        for (int kt = 0; kt < 8; ++kt) {
            bf16x8 b0 = *reinterpret_cast<const bf16x8*>(
                Wb1 + ((kt*4 + wn*2 + 0) << 10) + lane*16);
            bf16x8 b1 = *reinterpret_cast<const bf16x8*>(
                Wb1 + ((kt*4 + wn*2 + 1) << 10) + lane*16);
            #pragma unroll
            for (int mf = 0; mf < 2; ++mf) {
                acc1[mf][0] = mfma16(areg[mf][kt], b0, acc1[mf][0]);
                acc1[mf][1] = mfma16(areg[mf][kt], b1, acc1[mf][1]);
            }
        }
        // H = relu(acc1 + b1)*tw -> padded LDS bf16
        #pragma unroll
        for (int nf = 0; nf < 2; ++nf) {
            int col = (wn*2 + nf)*16 + lrow;       // chunk-local col (0..63)
            float bias = bias_lds[c*64 + col];
            #pragma unroll
            for (int mf = 0; mf < 2; ++mf)
                #pragma unroll
                for (int r = 0; r < 4; ++r) {
                    int row = wm*32 + mf*16 + g*4 + r;
                    float v = fmaxf(acc1[mf][nf][r] + bias, 0.f) * twl[row];
                    Hs[row*HSTR + col] = (short)f2bf(v);
                }
        }
        fence_sched();
        asm volatile("s_waitcnt lgkmcnt(0)" ::: "memory");   // W1 reads + H writes done
        fence_sched();
        __builtin_amdgcn_s_barrier();              // H visible; Wb1 free
        fence_sched();

        if (c + 1 < NCH) {
            stage_w1(c + 1);                       // hides under phase 2
            fence_sched();
            asm volatile("s_waitcnt vmcnt(8)" ::: "memory");   // W2(c) landed
        } else {
            fence_sched();
            asm volatile("s_waitcnt vmcnt(0)" ::: "memory");
        }
        fence_sched();
        __builtin_amdgcn_s_barrier();              // W2(c) visible
        fence_sched();

        // ---- phase 2 (2m x 2n): acc2 += H(64x64) @ W2c(64x256), 32r x 128c ----
        #pragma unroll
        for (int k2 = 0; k2 < 2; ++k2) {
            bf16x8 a2[2];
            #pragma unroll
            for (int mf = 0; mf < 2; ++mf)
                a2[mf] = *reinterpret_cast<const bf16x8*>(
                    Hs + (wm*32 + mf*16 + lrow)*HSTR + k2*32 + g*8);
            #pragma unroll
            for (int nf = 0; nf < 8; ++nf) {
                bf16x8 b2 = *reinterpret_cast<const bf16x8*>(
                    Wb2 + ((k2*16 + wn*8 + nf) << 10) + lane*16);
                #pragma unroll
                for (int mf = 0; mf < 2; ++mf)
                    acc2[mf][nf] = mfma16(a2[mf], b2, acc2[mf][nf]);
            }
        }
        fence_sched();
        __builtin_amdgcn_s_barrier();   // phase-2 reads retired -> H/Wb2 reusable
        fence_sched();
    }

    // ---- epilogue: one atomic pass (+ tw*b2) ----
    {
        const float* b2 = sh ? (sb2 + slot*OUTD) : (ib2 + (size_t)e*OUTD);
        #pragma unroll
        for (int mf = 0; mf < 2; ++mf)
            #pragma unroll
            for (int nf = 0; nf < 8; ++nf) {
                int col = wn*128 + nf*16 + lrow;
                #pragma unroll
                for (int r = 0; r < 4; ++r) {
                    int row = wm*32 + mf*16 + g*4 + r;
                    if (sh || (m0 + row < count)) {
                        int t = tokl[row];
                        float v = acc2[mf][nf][r] + twl[row] * b2[col];
                        atomicAdd(&out[(size_t)t*OUTD + col], v);
                    }
                }
            }
    }
}

extern "C" void kernel_launch(void* const* d_in, const int* in_sizes, int n_in,
                              void* d_out, int out_size, void* d_ws, size_t ws_size,
                              hipStream_t stream) {
    const float* x   = (const float*)d_in[0];
    const float* obj = (const float*)d_in[1];
    const float* gw  = (const float*)d_in[2];
    const float* gb  = (const float*)d_in[3];
    const float* sw1 = (const float*)d_in[4];
    const float* sb1 = (const float*)d_in[5];
    const float* sw2 = (const float*)d_in[6];
    const float* sb2 = (const float*)d_in[7];
    const float* iw1 = (const float*)d_in[8];
    const float* ib1 = (const float*)d_in[9];
    const float* iw2 = (const float*)d_in[10];
    const float* ib2 = (const float*)d_in[11];
    float* out = (float*)d_out;
    char* ws = (char*)d_ws;
    if (ws_size < WS_NEED) return;

    short* xb   = (short*)(ws + XB_OFF);
    short* w1p  = (short*)(ws + W1P_OFF);
    short* w2p  = (short*)(ws + W2P_OFF);
    float* wts  = (float*)(ws + WTS_OFF);
    int*   ids  = (int*)  (ws + IDS_OFF);
    int*   cnt  = (int*)  (ws + CNT_OFF);
    int*   ltok = (int*)  (ws + LTOK_OFF);
    float* lwt  = (float*)(ws + LW_OFF);

    hipMemsetAsync(ws + CNT_OFF, 0, 256, stream);
    hipMemsetAsync(out, 0, (size_t)out_size * 4, stream);
    k_prep<<<TOK/4, 256, 0, stream>>>(x, gw, gb, xb, wts, ids);
    k_convert_w<<<NSLOT*8*16 + NSLOT*32*4, 256, 0, stream>>>(sw1, iw1, sw2, iw2, w1p, w2p);
    k_route<<<TOK/256, 256, 0, stream>>>(ids, wts, cnt, ltok, lwt);
    k_moe<<<dim3(TOK/TM, NSLOT), 256, 0, stream>>>(
        xb, w1p, w2p, sb1, sb2, ib1, ib2, obj, cnt, ltok, lwt, out);
}

// Round 19
// 217.443 us; speedup vs baseline: 1.0558x; 1.0558x over previous
//
#include <hip/hip_runtime.h>
#include <hip/hip_bf16.h>
#include <stdint.h>

#define TOK   16384
#define DIM   256
#define HIDN  1024
#define OUTD  256
#define NEXP  8
#define NSH   3
#define NSLOT 11
#define TM    64
#define NCH   32      // hidden chunks of 32 cols
#define HSTR  40      // H row stride in shorts (80B: 16B-aligned, <=4-way banks)

typedef short bf16x8  __attribute__((ext_vector_type(8)));
typedef float f32x4   __attribute__((ext_vector_type(4)));
typedef float f32x16  __attribute__((ext_vector_type(16)));
typedef short short4v __attribute__((ext_vector_type(4)));

// ---- workspace layout (bytes) ----
constexpr size_t XB_OFF   = 0;                                        // T*D bf16
constexpr size_t W1P_OFF  = XB_OFF  + (size_t)TOK*DIM*2;
constexpr size_t W2P_OFF  = W1P_OFF + (size_t)NSLOT*DIM*HIDN*2;
constexpr size_t WTS_OFF  = W2P_OFF + (size_t)NSLOT*HIDN*OUTD*2;
constexpr size_t IDS_OFF  = WTS_OFF + (size_t)TOK*2*4;
constexpr size_t CNT_OFF  = IDS_OFF + (size_t)TOK*2*4;
constexpr size_t LTOK_OFF = CNT_OFF + 256;
constexpr size_t LW_OFF   = LTOK_OFF + (size_t)NEXP*TOK*4;
constexpr size_t WS_NEED  = LW_OFF + (size_t)NEXP*TOK*4;

__device__ __forceinline__ unsigned short f2bf(float f) {
    __hip_bfloat16 h = __float2bfloat16(f);
    return *reinterpret_cast<unsigned short*>(&h);
}

__device__ __forceinline__ f32x4 mfma16(bf16x8 a, bf16x8 b, f32x4 c) {
    return __builtin_amdgcn_mfma_f32_16x16x32_bf16(a, b, c, 0, 0, 0);
}
__device__ __forceinline__ f32x16 mfma32(bf16x8 a, bf16x8 b, f32x16 c) {
    return __builtin_amdgcn_mfma_f32_32x32x16_bf16(a, b, c, 0, 0, 0);
}

// async global->LDS: 16B/lane; global src per-lane, LDS dst uniform base.
__device__ __forceinline__ void gload_lds16(const void* g, void* l) {
    __builtin_amdgcn_global_load_lds(
        (const __attribute__((address_space(1))) unsigned int*)g,
        (__attribute__((address_space(3))) unsigned int*)l, 16, 0, 0);
}

__device__ __forceinline__ void fence_sched() { __builtin_amdgcn_sched_barrier(0); }

// ---- fused: fp32->bf16 convert of X + fp32-exact gating (one X pass) ----
__global__ __launch_bounds__(256) void k_prep(
    const float* __restrict__ x, const float* __restrict__ gw,
    const float* __restrict__ gb, short* __restrict__ xb,
    float* __restrict__ wts, int* __restrict__ ids) {
    int wid = threadIdx.x >> 6, lane = threadIdx.x & 63;
    int t = blockIdx.x * 4 + wid;
    const float* xr = x + (size_t)t * DIM;
    {
        float4 v = reinterpret_cast<const float4*>(xr)[lane];
        short4v o;
        o[0] = (short)f2bf(v.x); o[1] = (short)f2bf(v.y);
        o[2] = (short)f2bf(v.z); o[3] = (short)f2bf(v.w);
        reinterpret_cast<short4v*>(xb + (size_t)t * DIM)[lane] = o;
    }
    float acc[NEXP] = {0.f,0.f,0.f,0.f,0.f,0.f,0.f,0.f};
    #pragma unroll
    for (int i = 0; i < DIM/64; ++i) {
        int d = i*64 + lane;
        float xv = xr[d];
        const float* g = gw + (size_t)d * NEXP;
        #pragma unroll
        for (int e = 0; e < NEXP; ++e) acc[e] = fmaf(xv, g[e], acc[e]);
    }
    #pragma unroll
    for (int off = 32; off; off >>= 1) {
        #pragma unroll
        for (int e = 0; e < NEXP; ++e) acc[e] += __shfl_xor(acc[e], off, 64);
    }
    if (lane == 0) {
        float l[NEXP];
        #pragma unroll
        for (int e = 0; e < NEXP; ++e) l[e] = acc[e] + gb[e];
        int e0 = 0; float v0 = l[0];
        #pragma unroll
        for (int e = 1; e < NEXP; ++e) if (l[e] > v0) { v0 = l[e]; e0 = e; }
        int e1 = -1; float v1 = -1e30f;
        #pragma unroll
        for (int e = 0; e < NEXP; ++e) if (e != e0 && l[e] > v1) { v1 = l[e]; e1 = e; }
        float r = expf(v1 - v0);
        float w0 = 0.5f / (1.f + r);
        float w1 = 0.5f * r / (1.f + r);
        ids[2*t]   = e0;  ids[2*t+1] = e1;
        wts[2*t]   = w0;  wts[2*t+1] = w1;
    }
}

// ---- fp32 weights -> bf16 packed B-frag order, via LDS transpose ----
// W1: 16x16x32 frags (n=nt*16+(lane&15), k=kt*32+8*(lane>>4)+j), KT=8,NT=64.
// W2: 32x32x16 frags (n=nt*32+(lane&31), k=kt*16+8*(lane>>5)+j), KT=64,NT=8.
__global__ __launch_bounds__(256) void k_convert_w(
    const float* __restrict__ sw1, const float* __restrict__ iw1,
    const float* __restrict__ sw2, const float* __restrict__ iw2,
    short* __restrict__ w1p, short* __restrict__ w2p) {
    __shared__ float tile[32][68];
    int bid = blockIdx.x, tid = threadIdx.x;
    const int W1B = NSLOT * 8 * 16;            // 1408
    bool isW1 = bid < W1B;
    int b = isW1 ? bid : bid - W1B;
    int NTG = isW1 ? 16 : 4;
    int KT  = isW1 ? 8 : 32;                   // 32-k-row super-blocks
    int Nd  = isW1 ? HIDN : OUTD;
    int ntg = b % NTG; b /= NTG;
    int kt  = b % KT;
    int slot = b / KT;
    const float* src;
    if (isW1) src = (slot < NSH) ? sw1 + (size_t)slot*DIM*HIDN  : iw1 + (size_t)(slot-NSH)*DIM*HIDN;
    else      src = (slot < NSH) ? sw2 + (size_t)slot*HIDN*OUTD : iw2 + (size_t)(slot-NSH)*HIDN*OUTD;
    {
        int tr = tid >> 3, tc = (tid & 7) * 8;
        const float* s = src + (size_t)(kt*32 + tr)*Nd + ntg*64 + tc;
        float4 v0 = *reinterpret_cast<const float4*>(s);
        float4 v1 = *reinterpret_cast<const float4*>(s + 4);
        *reinterpret_cast<float4*>(&tile[tr][tc])     = v0;
        *reinterpret_cast<float4*>(&tile[tr][tc + 4]) = v1;
    }
    __syncthreads();
    if (isW1) {
        int ntl = tid >> 6, lane = tid & 63;
        int n  = ntl*16 + (lane & 15);
        int k8 = (lane >> 4) * 8;
        bf16x8 o;
        #pragma unroll
        for (int j = 0; j < 8; ++j) o[j] = (short)f2bf(tile[k8 + j][n]);
        size_t gidx = (((size_t)slot*8 + kt)*64 + ntg*4 + ntl)*64 + lane;
        reinterpret_cast<bf16x8*>(w1p)[gidx] = o;
    } else {
        int sub = tid >> 6, lane = tid & 63;
        int kt_sub = sub >> 1, nt_sub = sub & 1;
        int n  = nt_sub*32 + (lane & 31);
        int k8 = kt_sub*16 + (lane >> 5) * 8;
        bf16x8 o;
        #pragma unroll
        for (int j = 0; j < 8; ++j) o[j] = (short)f2bf(tile[k8 + j][n]);
        size_t gidx = (((size_t)slot*64 + kt*2 + kt_sub)*8 + ntg*2 + nt_sub)*64 + lane;
        reinterpret_cast<bf16x8*>(w2p)[gidx] = o;
    }
}

// ---- route: LDS histogram -> 8 global atomics per block ----
__global__ __launch_bounds__(256) void k_route(
    const int* __restrict__ ids, const float* __restrict__ wts,
    int* __restrict__ cnt, int* __restrict__ ltok, float* __restrict__ lw) {
    __shared__ int lcnt[NEXP];
    __shared__ int gbase[NEXP];
    int tid = threadIdx.x;
    if (tid < NEXP) lcnt[tid] = 0;
    __syncthreads();
    int t = blockIdx.x * 256 + tid;
    int e0 = ids[2*t], e1 = ids[2*t+1];
    int p0 = atomicAdd(&lcnt[e0], 1);
    int p1 = atomicAdd(&lcnt[e1], 1);
    __syncthreads();
    if (tid < NEXP) gbase[tid] = atomicAdd(&cnt[tid], lcnt[tid]);
    __syncthreads();
    size_t o0 = (size_t)e0*TOK + gbase[e0] + p0;
    size_t o1 = (size_t)e1*TOK + gbase[e1] + p1;
    ltok[o0] = t;  lw[o0] = wts[2*t];
    ltok[o1] = t;  lw[o1] = wts[2*t+1];
}

// ---- mega-kernel v15: r17 phase-1 + 32x32x16 phase-2 with W2 global-direct.
// 32x32 MFMA = 2x FLOP per operand byte, half the instructions. W2 frags
// have ZERO intra-block reuse -> LDS staging was a pure round-trip tax;
// read global->VGPR (L2-hot). W1 dbuf + counted vmcnt(2) as r17 (proven).
// LDS 42.5KB, regs ~120 incl AGPR -> 2 blocks/CU, 4 waves/SIMD.
__global__ __launch_bounds__(512) void k_moe(
    const short* __restrict__ xb, const short* __restrict__ w1p, const short* __restrict__ w2p,
    const float* __restrict__ sb1, const float* __restrict__ sb2,
    const float* __restrict__ ib1, const float* __restrict__ ib2,
    const float* __restrict__ obj, const int* __restrict__ cnt,
    const int* __restrict__ ltok, const float* __restrict__ lw,
    float* __restrict__ out)
{
    __shared__ __align__(16) char Wb1[2][16384];   // [kt 0..7][ntl 0..1] x 1KB
    __shared__ __align__(16) short Hs[TM * HSTR];  // 64 x 40 shorts (80B stride)
    __shared__ float bias_lds[HIDN];               // b1 (4KB)
    __shared__ int   tokl[TM];
    __shared__ float twl[TM];

    const int slot = blockIdx.y;
    const int m0   = blockIdx.x * TM;
    const bool sh  = slot < NSH;
    const int e    = slot - NSH;
    int count = TOK;
    if (!sh) { count = cnt[e]; if (m0 >= count) return; }

    const int tid  = threadIdx.x;
    const int w    = tid >> 6, lane = tid & 63;
    const int wm   = w >> 1,   wn   = w & 1;       // phase-1: 4m x 2n (16r x 16c)
    const int pmr  = w & 1,    pnc  = w >> 1;      // phase-2: 2m x 4n (32r x 64c), 32x32 tiles
    const int lrow = lane & 15, g   = lane >> 4;
    const int l31  = lane & 31, hi  = lane >> 5;

    if (tid < TM) {
        if (sh) {
            tokl[tid] = m0 + tid;
            twl[tid]  = 0.5f * obj[(size_t)(m0 + tid)*NSH + slot];
        } else {
            int p = m0 + tid;
            bool ok = p < count;
            tokl[tid] = ok ? ltok[(size_t)e*TOK + p] : 0;
            twl[tid]  = ok ? lw[(size_t)e*TOK + p] : 0.f;   // already 0.5-scaled
        }
    }
    __syncthreads();                               // tokl visible

    const char* w1base = (const char*)w1p;
    const char* w2base = (const char*)w2p;
    const float* b1v = sh ? (sb1 + slot*HIDN) : (ib1 + (size_t)e*HIDN);

    // ---- A-frags of this wave -> registers, once (chunk-invariant) ----
    const int tokA = tokl[wm*16 + lrow];
    bf16x8 areg[8];
    #pragma unroll
    for (int kt = 0; kt < 8; ++kt)
        areg[kt] = *reinterpret_cast<const bf16x8*>(
            xb + (size_t)tokA*DIM + kt*32 + g*8);

    // bias 4KB: waves 0..3
    if (w < 4)
        gload_lds16((const char*)b1v + w*1024 + lane*16, (char*)bias_lds + w*1024);

    // stage W1 chunk c (16KB) into buf: wave w stages (kt=w, ntl=0,1)
    auto stage_w1 = [&](int c, int buf) {
        #pragma unroll
        for (int i = 0; i < 2; ++i)
            gload_lds16(
                w1base + ((((size_t)slot*8 + w)*64 + c*2 + i) << 10) + lane*16,
                Wb1[buf] + ((w*2 + i) << 10));
    };

    // hard drain: areg/bias complete; later VMEM = W1 stages + W2 frag loads
    asm volatile("s_waitcnt vmcnt(0) lgkmcnt(0)" ::: "memory");
    __syncthreads();

    stage_w1(0, 0);
    stage_w1(1, 1);

    f32x16 acc2[2] = {};                           // 2 x (32x32) tiles: (pmr, pnc*2+j)
    for (int c = 0; c < NCH; ++c) {
        const int p = c & 1;
        // top: W1(c) must be landed; outstanding = W1(c+1)'s 2 gloads
        if (c + 1 < NCH) { fence_sched(); asm volatile("s_waitcnt vmcnt(2)" ::: "memory"); }
        else             { fence_sched(); asm volatile("s_waitcnt vmcnt(0)" ::: "memory"); }
        fence_sched();
        __builtin_amdgcn_s_barrier();              // W1(c) visible to all
        fence_sched();

        // ---- phase 1 (4m x 2n): acc1 = X(regs) @ W1c, wave 16r x 16c ----
        f32x4 acc1 = {};
        #pragma unroll
        for (int kt = 0; kt < 8; ++kt) {
            bf16x8 b = *reinterpret_cast<const bf16x8*>(
                Wb1[p] + ((kt*2 + wn) << 10) + lane*16);
            acc1 = mfma16(areg[kt], b, acc1);
        }
        // H = relu(acc1 + b1)*tw -> padded LDS bf16
        {
            int col = wn*16 + lrow;
            float bias = bias_lds[c*32 + col];
            #pragma unroll
            for (int r = 0; r < 4; ++r) {
                int row = wm*16 + g*4 + r;
                float v = fmaxf(acc1[r] + bias, 0.f) * twl[row];
                Hs[row*HSTR + col] = (short)f2bf(v);
            }
        }
        fence_sched();
        asm volatile("s_waitcnt lgkmcnt(0)" ::: "memory");   // W1 reads + H writes done
        fence_sched();
        __builtin_amdgcn_s_barrier();              // H visible; Wb1[p] free
        fence_sched();

        if (c + 2 < NCH) stage_w1(c + 2, p);       // hides under phase 2
        fence_sched();

        // ---- phase 2: 32x32x16, wave tile 32r x 64c (2 tiles), W2 global ----
        {
            // prefetch 4 W2 frags (ks 0..1 x tile j 0..1) from global (L2-hot)
            bf16x8 wf[2][2];
            #pragma unroll
            for (int ks = 0; ks < 2; ++ks)
                #pragma unroll
                for (int j = 0; j < 2; ++j)
                    wf[ks][j] = *reinterpret_cast<const bf16x8*>(
                        w2base + ((((size_t)slot*64 + c*2 + ks)*8 + pnc*2 + j) << 10) + lane*16);
            #pragma unroll
            for (int ks = 0; ks < 2; ++ks) {
                bf16x8 av = *reinterpret_cast<const bf16x8*>(
                    Hs + (pmr*32 + l31)*HSTR + ks*16 + hi*8);
                acc2[0] = mfma32(av, wf[ks][0], acc2[0]);
                acc2[1] = mfma32(av, wf[ks][1], acc2[1]);
            }
        }
        fence_sched();
        asm volatile("s_waitcnt lgkmcnt(0)" ::: "memory");   // H reads done
        fence_sched();
        __builtin_amdgcn_s_barrier();   // -> H reusable next chunk
        fence_sched();
    }

    // ---- epilogue: one atomic pass (+ tw*b2), 32x32 C/D layout ----
    // C/D: col = lane&31, row = (reg&3) + 8*(reg>>2) + 4*(lane>>5)  [m74/m101]
    {
        const float* b2 = sh ? (sb2 + slot*OUTD) : (ib2 + (size_t)e*OUTD);
        #pragma unroll
        for (int j = 0; j < 2; ++j) {
            int col = pnc*64 + j*32 + l31;
            float b2v = b2[col];
            #pragma unroll
            for (int r = 0; r < 16; ++r) {
                int row = pmr*32 + (r & 3) + 8*(r >> 2) + 4*hi;
                if (sh || (m0 + row < count)) {
                    int t = tokl[row];
                    float v = acc2[j][r] + twl[row] * b2v;
                    atomicAdd(&out[(size_t)t*OUTD + col], v);
                }
            }
        }
    }
}

extern "C" void kernel_launch(void* const* d_in, const int* in_sizes, int n_in,
                              void* d_out, int out_size, void* d_ws, size_t ws_size,
                              hipStream_t stream) {
    const float* x   = (const float*)d_in[0];
    const float* obj = (const float*)d_in[1];
    const float* gw  = (const float*)d_in[2];
    const float* gb  = (const float*)d_in[3];
    const float* sw1 = (const float*)d_in[4];
    const float* sb1 = (const float*)d_in[5];
    const float* sw2 = (const float*)d_in[6];
    const float* sb2 = (const float*)d_in[7];
    const float* iw1 = (const float*)d_in[8];
    const float* ib1 = (const float*)d_in[9];
    const float* iw2 = (const float*)d_in[10];
    const float* ib2 = (const float*)d_in[11];
    float* out = (float*)d_out;
    char* ws = (char*)d_ws;
    if (ws_size < WS_NEED) return;

    short* xb   = (short*)(ws + XB_OFF);
    short* w1p  = (short*)(ws + W1P_OFF);
    short* w2p  = (short*)(ws + W2P_OFF);
    float* wts  = (float*)(ws + WTS_OFF);
    int*   ids  = (int*)  (ws + IDS_OFF);
    int*   cnt  = (int*)  (ws + CNT_OFF);
    int*   ltok = (int*)  (ws + LTOK_OFF);
    float* lwt  = (float*)(ws + LW_OFF);

    hipMemsetAsync(ws + CNT_OFF, 0, 256, stream);
    hipMemsetAsync(out, 0, (size_t)out_size * 4, stream);
    k_prep<<<TOK/4, 256, 0, stream>>>(x, gw, gb, xb, wts, ids);
    k_convert_w<<<NSLOT*8*16 + NSLOT*32*4, 256, 0, stream>>>(sw1, iw1, sw2, iw2, w1p, w2p);
    k_route<<<TOK/256, 256, 0, stream>>>(ids, wts, cnt, ltok, lwt);
    k_moe<<<dim3(TOK/TM, NSLOT), 512, 0, stream>>>(
        xb, w1p, w2p, sb1, sb2, ib1, ib2, obj, cnt, ltok, lwt, out);
}

// Round 20
// 215.217 us; speedup vs baseline: 1.0667x; 1.0103x over previous
//
#include <hip/hip_runtime.h>
#include <hip/hip_bf16.h>
#include <stdint.h>

#define TOK   16384
#define DIM   256
#define HIDN  1024
#define OUTD  256
#define NEXP  8
#define NSH   3
#define NSLOT 11
#define TM    64
#define NCH   32      // hidden chunks of 32 cols
#define HSTR  40      // H row stride in shorts (80B: 16B-aligned)

typedef short bf16x8  __attribute__((ext_vector_type(8)));
typedef float f32x4   __attribute__((ext_vector_type(4)));
typedef float f32x16  __attribute__((ext_vector_type(16)));
typedef short short4v __attribute__((ext_vector_type(4)));

// ---- workspace layout (bytes) ----
constexpr size_t XB_OFF   = 0;                                        // T*D bf16
constexpr size_t W1P_OFF  = XB_OFF  + (size_t)TOK*DIM*2;
constexpr size_t W2P_OFF  = W1P_OFF + (size_t)NSLOT*DIM*HIDN*2;
constexpr size_t WTS_OFF  = W2P_OFF + (size_t)NSLOT*HIDN*OUTD*2;
constexpr size_t IDS_OFF  = WTS_OFF + (size_t)TOK*2*4;
constexpr size_t CNT_OFF  = IDS_OFF + (size_t)TOK*2*4;
constexpr size_t LTOK_OFF = CNT_OFF + 256;
constexpr size_t LW_OFF   = LTOK_OFF + (size_t)NEXP*TOK*4;
constexpr size_t WS_NEED  = LW_OFF + (size_t)NEXP*TOK*4;

__device__ __forceinline__ unsigned short f2bf(float f) {
    __hip_bfloat16 h = __float2bfloat16(f);
    return *reinterpret_cast<unsigned short*>(&h);
}

__device__ __forceinline__ f32x4 mfma16(bf16x8 a, bf16x8 b, f32x4 c) {
    return __builtin_amdgcn_mfma_f32_16x16x32_bf16(a, b, c, 0, 0, 0);
}
__device__ __forceinline__ f32x16 mfma32(bf16x8 a, bf16x8 b, f32x16 c) {
    return __builtin_amdgcn_mfma_f32_32x32x16_bf16(a, b, c, 0, 0, 0);
}

// async global->LDS: 16B/lane; global src per-lane, LDS dst uniform base.
__device__ __forceinline__ void gload_lds16(const void* g, void* l) {
    __builtin_amdgcn_global_load_lds(
        (const __attribute__((address_space(1))) unsigned int*)g,
        (__attribute__((address_space(3))) unsigned int*)l, 16, 0, 0);
}

__device__ __forceinline__ void fence_sched() { __builtin_amdgcn_sched_barrier(0); }

// ---- fused: fp32->bf16 convert of X + fp32-exact gating (one X pass) ----
__global__ __launch_bounds__(256) void k_prep(
    const float* __restrict__ x, const float* __restrict__ gw,
    const float* __restrict__ gb, short* __restrict__ xb,
    float* __restrict__ wts, int* __restrict__ ids) {
    int wid = threadIdx.x >> 6, lane = threadIdx.x & 63;
    int t = blockIdx.x * 4 + wid;
    const float* xr = x + (size_t)t * DIM;
    {
        float4 v = reinterpret_cast<const float4*>(xr)[lane];
        short4v o;
        o[0] = (short)f2bf(v.x); o[1] = (short)f2bf(v.y);
        o[2] = (short)f2bf(v.z); o[3] = (short)f2bf(v.w);
        reinterpret_cast<short4v*>(xb + (size_t)t * DIM)[lane] = o;
    }
    float acc[NEXP] = {0.f,0.f,0.f,0.f,0.f,0.f,0.f,0.f};
    #pragma unroll
    for (int i = 0; i < DIM/64; ++i) {
        int d = i*64 + lane;
        float xv = xr[d];
        const float* g = gw + (size_t)d * NEXP;
        #pragma unroll
        for (int e = 0; e < NEXP; ++e) acc[e] = fmaf(xv, g[e], acc[e]);
    }
    #pragma unroll
    for (int off = 32; off; off >>= 1) {
        #pragma unroll
        for (int e = 0; e < NEXP; ++e) acc[e] += __shfl_xor(acc[e], off, 64);
    }
    if (lane == 0) {
        float l[NEXP];
        #pragma unroll
        for (int e = 0; e < NEXP; ++e) l[e] = acc[e] + gb[e];
        int e0 = 0; float v0 = l[0];
        #pragma unroll
        for (int e = 1; e < NEXP; ++e) if (l[e] > v0) { v0 = l[e]; e0 = e; }
        int e1 = -1; float v1 = -1e30f;
        #pragma unroll
        for (int e = 0; e < NEXP; ++e) if (e != e0 && l[e] > v1) { v1 = l[e]; e1 = e; }
        float r = expf(v1 - v0);
        float w0 = 0.5f / (1.f + r);
        float w1 = 0.5f * r / (1.f + r);
        ids[2*t]   = e0;  ids[2*t+1] = e1;
        wts[2*t]   = w0;  wts[2*t+1] = w1;
    }
}

// ---- fp32 weights -> bf16 packed B-frag order, via LDS transpose ----
// W1: 16x16x32 frags (n=nt*16+(lane&15), k=kt*32+8*(lane>>4)+j), KT=8,NT=64.
// W2: 32x32x16 frags (n=nt*32+(lane&31), k=kt*16+8*(lane>>5)+j), KT=64,NT=8.
__global__ __launch_bounds__(256) void k_convert_w(
    const float* __restrict__ sw1, const float* __restrict__ iw1,
    const float* __restrict__ sw2, const float* __restrict__ iw2,
    short* __restrict__ w1p, short* __restrict__ w2p) {
    __shared__ float tile[32][68];
    int bid = blockIdx.x, tid = threadIdx.x;
    const int W1B = NSLOT * 8 * 16;            // 1408
    bool isW1 = bid < W1B;
    int b = isW1 ? bid : bid - W1B;
    int NTG = isW1 ? 16 : 4;
    int KT  = isW1 ? 8 : 32;                   // 32-k-row super-blocks
    int Nd  = isW1 ? HIDN : OUTD;
    int ntg = b % NTG; b /= NTG;
    int kt  = b % KT;
    int slot = b / KT;
    const float* src;
    if (isW1) src = (slot < NSH) ? sw1 + (size_t)slot*DIM*HIDN  : iw1 + (size_t)(slot-NSH)*DIM*HIDN;
    else      src = (slot < NSH) ? sw2 + (size_t)slot*HIDN*OUTD : iw2 + (size_t)(slot-NSH)*HIDN*OUTD;
    {
        int tr = tid >> 3, tc = (tid & 7) * 8;
        const float* s = src + (size_t)(kt*32 + tr)*Nd + ntg*64 + tc;
        float4 v0 = *reinterpret_cast<const float4*>(s);
        float4 v1 = *reinterpret_cast<const float4*>(s + 4);
        *reinterpret_cast<float4*>(&tile[tr][tc])     = v0;
        *reinterpret_cast<float4*>(&tile[tr][tc + 4]) = v1;
    }
    __syncthreads();
    if (isW1) {
        int ntl = tid >> 6, lane = tid & 63;
        int n  = ntl*16 + (lane & 15);
        int k8 = (lane >> 4) * 8;
        bf16x8 o;
        #pragma unroll
        for (int j = 0; j < 8; ++j) o[j] = (short)f2bf(tile[k8 + j][n]);
        size_t gidx = (((size_t)slot*8 + kt)*64 + ntg*4 + ntl)*64 + lane;
        reinterpret_cast<bf16x8*>(w1p)[gidx] = o;
    } else {
        int sub = tid >> 6, lane = tid & 63;
        int kt_sub = sub >> 1, nt_sub = sub & 1;
        int n  = nt_sub*32 + (lane & 31);
        int k8 = kt_sub*16 + (lane >> 5) * 8;
        bf16x8 o;
        #pragma unroll
        for (int j = 0; j < 8; ++j) o[j] = (short)f2bf(tile[k8 + j][n]);
        size_t gidx = (((size_t)slot*64 + kt*2 + kt_sub)*8 + ntg*2 + nt_sub)*64 + lane;
        reinterpret_cast<bf16x8*>(w2p)[gidx] = o;
    }
}

// ---- route: LDS histogram -> 8 global atomics per block ----
__global__ __launch_bounds__(256) void k_route(
    const int* __restrict__ ids, const float* __restrict__ wts,
    int* __restrict__ cnt, int* __restrict__ ltok, float* __restrict__ lw) {
    __shared__ int lcnt[NEXP];
    __shared__ int gbase[NEXP];
    int tid = threadIdx.x;
    if (tid < NEXP) lcnt[tid] = 0;
    __syncthreads();
    int t = blockIdx.x * 256 + tid;
    int e0 = ids[2*t], e1 = ids[2*t+1];
    int p0 = atomicAdd(&lcnt[e0], 1);
    int p1 = atomicAdd(&lcnt[e1], 1);
    __syncthreads();
    if (tid < NEXP) gbase[tid] = atomicAdd(&cnt[tid], lcnt[tid]);
    __syncthreads();
    size_t o0 = (size_t)e0*TOK + gbase[e0] + p0;
    size_t o1 = (size_t)e1*TOK + gbase[e1] + p1;
    ltok[o0] = t;  lw[o0] = wts[2*t];
    ltok[o1] = t;  lw[o1] = wts[2*t+1];
}

// ---- mega-kernel v16: ONE barrier per chunk; phases merged into a single
// scheduling region via H double-buffer. Iter s: phase1(s) writes Hs[s&1];
// phase2(s-1) reads Hs[(s-1)&1] + W2(s-1) global frags. The top-of-iter
// barrier (vmcnt0+lgkm0 drained) provides ALL fencing: H write->read (1 iter
// apart), H read->overwrite (2 apart), W1 stage->read (1 apart), W1
// read->restage (stage issued AFTER the barrier; prior readers drained).
// Phase-1's serial 8-MFMA chain now co-schedules with phase-2's independent
// mfma32s -> latency hidden without extra waves.
__global__ __launch_bounds__(512) void k_moe(
    const short* __restrict__ xb, const short* __restrict__ w1p, const short* __restrict__ w2p,
    const float* __restrict__ sb1, const float* __restrict__ sb2,
    const float* __restrict__ ib1, const float* __restrict__ ib2,
    const float* __restrict__ obj, const int* __restrict__ cnt,
    const int* __restrict__ ltok, const float* __restrict__ lw,
    float* __restrict__ out)
{
    __shared__ __align__(16) char Wb1[2][16384];   // [kt 0..7][ntl 0..1] x 1KB
    __shared__ __align__(16) short Hs[2][TM * HSTR]; // 2 x 64 x 40 shorts
    __shared__ float bias_lds[HIDN];               // b1 (4KB)
    __shared__ int   tokl[TM];
    __shared__ float twl[TM];

    const int slot = blockIdx.y;
    const int m0   = blockIdx.x * TM;
    const bool sh  = slot < NSH;
    const int e    = slot - NSH;
    int count = TOK;
    if (!sh) { count = cnt[e]; if (m0 >= count) return; }

    const int tid  = threadIdx.x;
    const int w    = tid >> 6, lane = tid & 63;
    const int wm   = w >> 1,   wn   = w & 1;       // phase-1: 4m x 2n (16r x 16c)
    const int pmr  = w & 1,    pnc  = w >> 1;      // phase-2: 2m x 4n (32r x 64c)
    const int lrow = lane & 15, g   = lane >> 4;
    const int l31  = lane & 31, hi  = lane >> 5;

    if (tid < TM) {
        if (sh) {
            tokl[tid] = m0 + tid;
            twl[tid]  = 0.5f * obj[(size_t)(m0 + tid)*NSH + slot];
        } else {
            int p = m0 + tid;
            bool ok = p < count;
            tokl[tid] = ok ? ltok[(size_t)e*TOK + p] : 0;
            twl[tid]  = ok ? lw[(size_t)e*TOK + p] : 0.f;   // already 0.5-scaled
        }
    }
    __syncthreads();                               // tokl visible

    const char* w1base = (const char*)w1p;
    const char* w2base = (const char*)w2p;
    const float* b1v = sh ? (sb1 + slot*HIDN) : (ib1 + (size_t)e*HIDN);

    // ---- A-frags of this wave -> registers, once (chunk-invariant) ----
    const int tokA = tokl[wm*16 + lrow];
    bf16x8 areg[8];
    #pragma unroll
    for (int kt = 0; kt < 8; ++kt)
        areg[kt] = *reinterpret_cast<const bf16x8*>(
            xb + (size_t)tokA*DIM + kt*32 + g*8);

    // bias 4KB: waves 0..3
    if (w < 4)
        gload_lds16((const char*)b1v + w*1024 + lane*16, (char*)bias_lds + w*1024);

    // stage W1 chunk c (16KB) into buf: wave w stages (kt=w, ntl=0,1)
    auto stage_w1 = [&](int c, int buf) {
        #pragma unroll
        for (int i = 0; i < 2; ++i)
            gload_lds16(
                w1base + ((((size_t)slot*8 + w)*64 + c*2 + i) << 10) + lane*16,
                Wb1[buf] + ((w*2 + i) << 10));
    };

    // hard drain: areg/bias complete
    asm volatile("s_waitcnt vmcnt(0) lgkmcnt(0)" ::: "memory");
    __syncthreads();

    stage_w1(0, 0);

    f32x16 acc2[2] = {};                           // 2 x (32x32) tiles
    for (int s = 0; s <= NCH; ++s) {
        // single per-iter fence: all VMEM landed (W1(s) staged last iter,
        // W2 frags consumed), all DS ops drained (H writes of s-1 visible,
        // H/W1 reads of s-1 retired before any overwrite)
        fence_sched();
        asm volatile("s_waitcnt vmcnt(0) lgkmcnt(0)" ::: "memory");
        fence_sched();
        __builtin_amdgcn_s_barrier();
        fence_sched();
        if (s + 1 < NCH) stage_w1(s + 1, (s + 1) & 1);  // after barrier: prior readers drained

        // ---- phase 1 (chunk s): acc1 = X(regs) @ W1(s), H -> Hs[s&1] ----
        if (s < NCH) {
            f32x4 acc1 = {};
            #pragma unroll
            for (int kt = 0; kt < 8; ++kt) {
                bf16x8 b = *reinterpret_cast<const bf16x8*>(
                    Wb1[s & 1] + ((kt*2 + wn) << 10) + lane*16);
                acc1 = mfma16(areg[kt], b, acc1);
            }
            int col = wn*16 + lrow;
            float bias = bias_lds[s*32 + col];
            short* hb = Hs[s & 1];
            #pragma unroll
            for (int r = 0; r < 4; ++r) {
                int row = wm*16 + g*4 + r;
                float v = fmaxf(acc1[r] + bias, 0.f) * twl[row];
                hb[row*HSTR + col] = (short)f2bf(v);
            }
        }

        // ---- phase 2 (chunk d=s-1): acc2 += H(d) @ W2(d), W2 global ----
        if (s >= 1) {
            const int d = s - 1;
            const short* hb = Hs[d & 1];
            bf16x8 wf[2][2];
            #pragma unroll
            for (int ks = 0; ks < 2; ++ks)
                #pragma unroll
                for (int j = 0; j < 2; ++j)
                    wf[ks][j] = *reinterpret_cast<const bf16x8*>(
                        w2base + ((((size_t)slot*64 + d*2 + ks)*8 + pnc*2 + j) << 10) + lane*16);
            #pragma unroll
            for (int ks = 0; ks < 2; ++ks) {
                bf16x8 av = *reinterpret_cast<const bf16x8*>(
                    hb + (pmr*32 + l31)*HSTR + ks*16 + hi*8);
                acc2[0] = mfma32(av, wf[ks][0], acc2[0]);
                acc2[1] = mfma32(av, wf[ks][1], acc2[1]);
            }
        }
    }

    // ---- epilogue: one atomic pass (+ tw*b2), 32x32 C/D layout ----
    // C/D: col = lane&31, row = (reg&3) + 8*(reg>>2) + 4*(lane>>5)  [m74/m101]
    {
        const float* b2 = sh ? (sb2 + slot*OUTD) : (ib2 + (size_t)e*OUTD);
        #pragma unroll
        for (int j = 0; j < 2; ++j) {
            int col = pnc*64 + j*32 + l31;
            float b2v = b2[col];
            #pragma unroll
            for (int r = 0; r < 16; ++r) {
                int row = pmr*32 + (r & 3) + 8*(r >> 2) + 4*hi;
                if (sh || (m0 + row < count)) {
                    int t = tokl[row];
                    float v = acc2[j][r] + twl[row] * b2v;
                    atomicAdd(&out[(size_t)t*OUTD + col], v);
                }
            }
        }
    }
}

extern "C" void kernel_launch(void* const* d_in, const int* in_sizes, int n_in,
                              void* d_out, int out_size, void* d_ws, size_t ws_size,
                              hipStream_t stream) {
    const float* x   = (const float*)d_in[0];
    const float* obj = (const float*)d_in[1];
    const float* gw  = (const float*)d_in[2];
    const float* gb  = (const float*)d_in[3];
    const float* sw1 = (const float*)d_in[4];
    const float* sb1 = (const float*)d_in[5];
    const float* sw2 = (const float*)d_in[6];
    const float* sb2 = (const float*)d_in[7];
    const float* iw1 = (const float*)d_in[8];
    const float* ib1 = (const float*)d_in[9];
    const float* iw2 = (const float*)d_in[10];
    const float* ib2 = (const float*)d_in[11];
    float* out = (float*)d_out;
    char* ws = (char*)d_ws;
    if (ws_size < WS_NEED) return;

    short* xb   = (short*)(ws + XB_OFF);
    short* w1p  = (short*)(ws + W1P_OFF);
    short* w2p  = (short*)(ws + W2P_OFF);
    float* wts  = (float*)(ws + WTS_OFF);
    int*   ids  = (int*)  (ws + IDS_OFF);
    int*   cnt  = (int*)  (ws + CNT_OFF);
    int*   ltok = (int*)  (ws + LTOK_OFF);
    float* lwt  = (float*)(ws + LW_OFF);

    hipMemsetAsync(ws + CNT_OFF, 0, 256, stream);
    hipMemsetAsync(out, 0, (size_t)out_size * 4, stream);
    k_prep<<<TOK/4, 256, 0, stream>>>(x, gw, gb, xb, wts, ids);
    k_convert_w<<<NSLOT*8*16 + NSLOT*32*4, 256, 0, stream>>>(sw1, iw1, sw2, iw2, w1p, w2p);
    k_route<<<TOK/256, 256, 0, stream>>>(ids, wts, cnt, ltok, lwt);
    k_moe<<<dim3(TOK/TM, NSLOT), 512, 0, stream>>>(
        xb, w1p, w2p, sb1, sb2, ib1, ib2, obj, cnt, ltok, lwt, out);
}

// Round 21
// 205.776 us; speedup vs baseline: 1.1157x; 1.0459x over previous
//
#include <hip/hip_runtime.h>
#include <hip/hip_bf16.h>
#include <stdint.h>

#define TOK   16384
#define DIM   256
#define HIDN  1024
#define OUTD  256
#define NEXP  8
#define NSH   3
#define NSLOT 11
#define TM    64
#define NCH   32      // hidden chunks of 32 cols
#define HSTR  40      // H row stride in shorts (80B: 16B-aligned, <=2-way banks)

typedef short bf16x8  __attribute__((ext_vector_type(8)));
typedef float f32x4   __attribute__((ext_vector_type(4)));
typedef short short4v __attribute__((ext_vector_type(4)));

// ---- workspace layout (bytes) ----
constexpr size_t XB_OFF   = 0;                                        // T*D bf16
constexpr size_t W1P_OFF  = XB_OFF  + (size_t)TOK*DIM*2;
constexpr size_t W2P_OFF  = W1P_OFF + (size_t)NSLOT*DIM*HIDN*2;
constexpr size_t WTS_OFF  = W2P_OFF + (size_t)NSLOT*HIDN*OUTD*2;
constexpr size_t IDS_OFF  = WTS_OFF + (size_t)TOK*2*4;
constexpr size_t CNT_OFF  = IDS_OFF + (size_t)TOK*2*4;
constexpr size_t LTOK_OFF = CNT_OFF + 256;
constexpr size_t LW_OFF   = LTOK_OFF + (size_t)NEXP*TOK*4;
constexpr size_t WS_NEED  = LW_OFF + (size_t)NEXP*TOK*4;

__device__ __forceinline__ unsigned short f2bf(float f) {
    __hip_bfloat16 h = __float2bfloat16(f);
    return *reinterpret_cast<unsigned short*>(&h);
}

__device__ __forceinline__ f32x4 mfma16(bf16x8 a, bf16x8 b, f32x4 c) {
    return __builtin_amdgcn_mfma_f32_16x16x32_bf16(a, b, c, 0, 0, 0);
}

// async global->LDS: 16B/lane; global src per-lane, LDS dst uniform base.
__device__ __forceinline__ void gload_lds16(const void* g, void* l) {
    __builtin_amdgcn_global_load_lds(
        (const __attribute__((address_space(1))) unsigned int*)g,
        (__attribute__((address_space(3))) unsigned int*)l, 16, 0, 0);
}

__device__ __forceinline__ void fence_sched() { __builtin_amdgcn_sched_barrier(0); }

// ---- fused: fp32->bf16 convert of X + fp32-exact gating (one X pass) ----
__global__ __launch_bounds__(256) void k_prep(
    const float* __restrict__ x, const float* __restrict__ gw,
    const float* __restrict__ gb, short* __restrict__ xb,
    float* __restrict__ wts, int* __restrict__ ids) {
    int wid = threadIdx.x >> 6, lane = threadIdx.x & 63;
    int t = blockIdx.x * 4 + wid;
    const float* xr = x + (size_t)t * DIM;
    {
        float4 v = reinterpret_cast<const float4*>(xr)[lane];
        short4v o;
        o[0] = (short)f2bf(v.x); o[1] = (short)f2bf(v.y);
        o[2] = (short)f2bf(v.z); o[3] = (short)f2bf(v.w);
        reinterpret_cast<short4v*>(xb + (size_t)t * DIM)[lane] = o;
    }
    float acc[NEXP] = {0.f,0.f,0.f,0.f,0.f,0.f,0.f,0.f};
    #pragma unroll
    for (int i = 0; i < DIM/64; ++i) {
        int d = i*64 + lane;
        float xv = xr[d];
        const float* g = gw + (size_t)d * NEXP;
        #pragma unroll
        for (int e = 0; e < NEXP; ++e) acc[e] = fmaf(xv, g[e], acc[e]);
    }
    #pragma unroll
    for (int off = 32; off; off >>= 1) {
        #pragma unroll
        for (int e = 0; e < NEXP; ++e) acc[e] += __shfl_xor(acc[e], off, 64);
    }
    if (lane == 0) {
        float l[NEXP];
        #pragma unroll
        for (int e = 0; e < NEXP; ++e) l[e] = acc[e] + gb[e];
        int e0 = 0; float v0 = l[0];
        #pragma unroll
        for (int e = 1; e < NEXP; ++e) if (l[e] > v0) { v0 = l[e]; e0 = e; }
        int e1 = -1; float v1 = -1e30f;
        #pragma unroll
        for (int e = 0; e < NEXP; ++e) if (e != e0 && l[e] > v1) { v1 = l[e]; e1 = e; }
        float r = expf(v1 - v0);
        float w0 = 0.5f / (1.f + r);
        float w1 = 0.5f * r / (1.f + r);
        ids[2*t]   = e0;  ids[2*t+1] = e1;
        wts[2*t]   = w0;  wts[2*t+1] = w1;
    }
}

// ---- fp32 weights -> bf16 packed B-frag order, via LDS transpose ----
__global__ __launch_bounds__(256) void k_convert_w(
    const float* __restrict__ sw1, const float* __restrict__ iw1,
    const float* __restrict__ sw2, const float* __restrict__ iw2,
    short* __restrict__ w1p, short* __restrict__ w2p) {
    __shared__ float tile[32][68];
    int bid = blockIdx.x, tid = threadIdx.x;
    const int W1B = NSLOT * 8 * 16;            // 1408
    bool isW1 = bid < W1B;
    int b = isW1 ? bid : bid - W1B;
    int NTG = isW1 ? 16 : 4;
    int KT  = isW1 ? 8 : 32;
    int NT  = isW1 ? 64 : 16;
    int Nd  = isW1 ? HIDN : OUTD;
    int ntg = b % NTG; b /= NTG;
    int kt  = b % KT;
    int slot = b / KT;
    const float* src;
    if (isW1) src = (slot < NSH) ? sw1 + (size_t)slot*DIM*HIDN  : iw1 + (size_t)(slot-NSH)*DIM*HIDN;
    else      src = (slot < NSH) ? sw2 + (size_t)slot*HIDN*OUTD : iw2 + (size_t)(slot-NSH)*HIDN*OUTD;
    {
        int tr = tid >> 3, tc = (tid & 7) * 8;
        const float* s = src + (size_t)(kt*32 + tr)*Nd + ntg*64 + tc;
        float4 v0 = *reinterpret_cast<const float4*>(s);
        float4 v1 = *reinterpret_cast<const float4*>(s + 4);
        *reinterpret_cast<float4*>(&tile[tr][tc])     = v0;
        *reinterpret_cast<float4*>(&tile[tr][tc + 4]) = v1;
    }
    __syncthreads();
    {
        int ntl = tid >> 6, lane = tid & 63;
        int n  = ntl*16 + (lane & 15);
        int k8 = (lane >> 4) * 8;
        bf16x8 o;
        #pragma unroll
        for (int j = 0; j < 8; ++j) o[j] = (short)f2bf(tile[k8 + j][n]);
        size_t gidx = (((size_t)slot*KT + kt)*NT + ntg*4 + ntl)*64 + lane;
        short* dst = isW1 ? w1p : w2p;
        reinterpret_cast<bf16x8*>(dst)[gidx] = o;
    }
}

// ---- route: LDS histogram -> 8 global atomics per block ----
__global__ __launch_bounds__(256) void k_route(
    const int* __restrict__ ids, const float* __restrict__ wts,
    int* __restrict__ cnt, int* __restrict__ ltok, float* __restrict__ lw) {
    __shared__ int lcnt[NEXP];
    __shared__ int gbase[NEXP];
    int tid = threadIdx.x;
    if (tid < NEXP) lcnt[tid] = 0;
    __syncthreads();
    int t = blockIdx.x * 256 + tid;
    int e0 = ids[2*t], e1 = ids[2*t+1];
    int p0 = atomicAdd(&lcnt[e0], 1);
    int p1 = atomicAdd(&lcnt[e1], 1);
    __syncthreads();
    if (tid < NEXP) gbase[tid] = atomicAdd(&cnt[tid], lcnt[tid]);
    __syncthreads();
    size_t o0 = (size_t)e0*TOK + gbase[e0] + p0;
    size_t o1 = (size_t)e1*TOK + gbase[e1] + p1;
    ltok[o0] = t;  lw[o0] = wts[2*t];
    ltok[o1] = t;  lw[o1] = wts[2*t+1];
}

// ---- mega-kernel v12 (best measured: r16, k_moe ~185us, total ~206us) ----
// A-frags hoisted to registers (areg[8]=32 VGPR, chunk-invariant); H rows
// padded to 80B; split counted-vmcnt staging (W1 at phase-2 start, W2 at
// chunk top, never vmcnt(0) mid-loop); balanced 2D grid; LDS 42.5KB ->
// 2 blocks/CU. Rounds 17-20 falsified: deeper dbuf (null), fat tiles
// (occupancy cliff), 32x32 phase-2 (slower), merged phases (null) -> this
// config is the structure's local optimum.
__global__ __launch_bounds__(512) void k_moe(
    const short* __restrict__ xb, const short* __restrict__ w1p, const short* __restrict__ w2p,
    const float* __restrict__ sb1, const float* __restrict__ sb2,
    const float* __restrict__ ib1, const float* __restrict__ ib2,
    const float* __restrict__ obj, const int* __restrict__ cnt,
    const int* __restrict__ ltok, const float* __restrict__ lw,
    float* __restrict__ out)
{
    __shared__ __align__(16) char Wb1[16384];      // [kt 0..7][ntl 0..1] x 1KB
    __shared__ __align__(16) char Wb2[16384];      // [nt 0..15] x 1KB
    __shared__ __align__(16) short Hs[TM * HSTR];  // 64 x 40 shorts (80B stride)
    __shared__ float bias_lds[HIDN];               // b1 (4KB)
    __shared__ int   tokl[TM];
    __shared__ float twl[TM];

    const int slot = blockIdx.y;
    const int m0   = blockIdx.x * TM;
    const bool sh  = slot < NSH;
    const int e    = slot - NSH;
    int count = TOK;
    if (!sh) { count = cnt[e]; if (m0 >= count) return; }

    const int tid  = threadIdx.x;
    const int w    = tid >> 6, lane = tid & 63;
    const int wm   = w >> 1,   wn   = w & 1;       // phase-1: 4m x 2n (16r x 16c)
    const int pm   = w >> 2,   pn   = w & 3;       // phase-2: 2m x 4n (32r x 64c)
    const int lrow = lane & 15, g   = lane >> 4;

    if (tid < TM) {
        if (sh) {
            tokl[tid] = m0 + tid;
            twl[tid]  = 0.5f * obj[(size_t)(m0 + tid)*NSH + slot];
        } else {
            int p = m0 + tid;
            bool ok = p < count;
            tokl[tid] = ok ? ltok[(size_t)e*TOK + p] : 0;
            twl[tid]  = ok ? lw[(size_t)e*TOK + p] : 0.f;   // already 0.5-scaled
        }
    }
    __syncthreads();                               // tokl visible

    const char* w1base = (const char*)w1p;
    const char* w2base = (const char*)w2p;
    const float* b1v = sh ? (sb1 + slot*HIDN) : (ib1 + (size_t)e*HIDN);

    // ---- A-frags of this wave -> registers, once (chunk-invariant) ----
    const int tokA = tokl[wm*16 + lrow];
    bf16x8 areg[8];
    #pragma unroll
    for (int kt = 0; kt < 8; ++kt)
        areg[kt] = *reinterpret_cast<const bf16x8*>(
            xb + (size_t)tokA*DIM + kt*32 + g*8);

    // bias 4KB: waves 0..3
    if (w < 4)
        gload_lds16((const char*)b1v + w*1024 + lane*16, (char*)bias_lds + w*1024);

    // stage W1 chunk c (16KB): wave w stages (kt=w, ntl=0,1)
    auto stage_w1 = [&](int c) {
        #pragma unroll
        for (int i = 0; i < 2; ++i)
            gload_lds16(
                w1base + ((((size_t)slot*8 + w)*64 + c*2 + i) << 10) + lane*16,
                Wb1 + ((w*2 + i) << 10));
    };
    // stage W2 chunk c (16KB): wave w stages nt = w*2, w*2+1
    auto stage_w2 = [&](int c) {
        const char* s2 = w2base + ((((size_t)slot*32 + c)*16) << 10);
        #pragma unroll
        for (int i = 0; i < 2; ++i)
            gload_lds16(s2 + ((w*2 + i) << 10) + lane*16, Wb2 + ((w*2 + i) << 10));
    };
    stage_w1(0);
    stage_w2(0);
    // hard drain: areg/bias/stage(0) complete; loop VMEM = staging only
    asm volatile("s_waitcnt vmcnt(0) lgkmcnt(0)" ::: "memory");
    __syncthreads();

    f32x4 acc2[2][4] = {};                         // phase-2 wave tile 32 x 64
    for (int c = 0; c < NCH; ++c) {
        if (c > 0) {
            stage_w2(c);                           // W2 buf free since last barrier
            fence_sched();
            asm volatile("s_waitcnt vmcnt(2)" ::: "memory");   // W1(c) landed
            fence_sched();
            __builtin_amdgcn_s_barrier();
            fence_sched();
        }

        // ---- phase 1 (4m x 2n): acc1 = X(regs) @ W1c, wave 16r x 16c ----
        f32x4 acc1 = {};
        #pragma unroll
        for (int kt = 0; kt < 8; ++kt) {
            bf16x8 b = *reinterpret_cast<const bf16x8*>(
                Wb1 + ((kt*2 + wn) << 10) + lane*16);
            acc1 = mfma16(areg[kt], b, acc1);
        }
        // H = relu(acc1 + b1)*tw -> padded LDS bf16
        {
            int col = wn*16 + lrow;
            float bias = bias_lds[c*32 + col];
            #pragma unroll
            for (int r = 0; r < 4; ++r) {
                int row = wm*16 + g*4 + r;
                float v = fmaxf(acc1[r] + bias, 0.f) * twl[row];
                Hs[row*HSTR + col] = (short)f2bf(v);
            }
        }
        fence_sched();
        asm volatile("s_waitcnt lgkmcnt(0)" ::: "memory");   // W1 reads + H writes done
        fence_sched();
        __builtin_amdgcn_s_barrier();
        fence_sched();

        if (c + 1 < NCH) stage_w1(c + 1);          // hides under phase 2
        fence_sched();
        if (c + 1 < NCH) { asm volatile("s_waitcnt vmcnt(2)" ::: "memory"); }
        else             { asm volatile("s_waitcnt vmcnt(0)" ::: "memory"); }
        fence_sched();
        __builtin_amdgcn_s_barrier();              // W2(c) + H visible
        fence_sched();

        // ---- phase 2 (2m x 4n): acc2 += H(64x32) @ W2c(32x256), 32r x 64c ----
        {
            bf16x8 a2[2];
            #pragma unroll
            for (int mf = 0; mf < 2; ++mf)
                a2[mf] = *reinterpret_cast<const bf16x8*>(
                    Hs + (pm*32 + mf*16 + lrow)*HSTR + g*8);
            #pragma unroll
            for (int nf = 0; nf < 4; ++nf) {
                bf16x8 b2 = *reinterpret_cast<const bf16x8*>(
                    Wb2 + ((pn*4 + nf) << 10) + lane*16);
                #pragma unroll
                for (int mf = 0; mf < 2; ++mf)
                    acc2[mf][nf] = mfma16(a2[mf], b2, acc2[mf][nf]);
            }
        }
        fence_sched();
        __builtin_amdgcn_s_barrier();   // phase-2 reads retired -> W2/H reusable
        fence_sched();
    }

    // ---- epilogue: one atomic pass (+ tw*b2), phase-2 mapping ----
    {
        const float* b2 = sh ? (sb2 + slot*OUTD) : (ib2 + (size_t)e*OUTD);
        #pragma unroll
        for (int mf = 0; mf < 2; ++mf)
            #pragma unroll
            for (int nf = 0; nf < 4; ++nf) {
                int col = pn*64 + nf*16 + lrow;
                #pragma unroll
                for (int r = 0; r < 4; ++r) {
                    int row = pm*32 + mf*16 + g*4 + r;
                    if (sh || (m0 + row < count)) {
                        int t = tokl[row];
                        float v = acc2[mf][nf][r] + twl[row] * b2[col];
                        atomicAdd(&out[(size_t)t*OUTD + col], v);
                    }
                }
            }
    }
}

extern "C" void kernel_launch(void* const* d_in, const int* in_sizes, int n_in,
                              void* d_out, int out_size, void* d_ws, size_t ws_size,
                              hipStream_t stream) {
    const float* x   = (const float*)d_in[0];
    const float* obj = (const float*)d_in[1];
    const float* gw  = (const float*)d_in[2];
    const float* gb  = (const float*)d_in[3];
    const float* sw1 = (const float*)d_in[4];
    const float* sb1 = (const float*)d_in[5];
    const float* sw2 = (const float*)d_in[6];
    const float* sb2 = (const float*)d_in[7];
    const float* iw1 = (const float*)d_in[8];
    const float* ib1 = (const float*)d_in[9];
    const float* iw2 = (const float*)d_in[10];
    const float* ib2 = (const float*)d_in[11];
    float* out = (float*)d_out;
    char* ws = (char*)d_ws;
    if (ws_size < WS_NEED) return;

    short* xb   = (short*)(ws + XB_OFF);
    short* w1p  = (short*)(ws + W1P_OFF);
    short* w2p  = (short*)(ws + W2P_OFF);
    float* wts  = (float*)(ws + WTS_OFF);
    int*   ids  = (int*)  (ws + IDS_OFF);
    int*   cnt  = (int*)  (ws + CNT_OFF);
    int*   ltok = (int*)  (ws + LTOK_OFF);
    float* lwt  = (float*)(ws + LW_OFF);

    hipMemsetAsync(ws + CNT_OFF, 0, 256, stream);
    hipMemsetAsync(out, 0, (size_t)out_size * 4, stream);
    k_prep<<<TOK/4, 256, 0, stream>>>(x, gw, gb, xb, wts, ids);
    k_convert_w<<<NSLOT*8*16 + NSLOT*32*4, 256, 0, stream>>>(sw1, iw1, sw2, iw2, w1p, w2p);
    k_route<<<TOK/256, 256, 0, stream>>>(ids, wts, cnt, ltok, lwt);
    k_moe<<<dim3(TOK/TM, NSLOT), 512, 0, stream>>>(
        xb, w1p, w2p, sb1, sb2, ib1, ib2, obj, cnt, ltok, lwt, out);
}